// Round 1
// baseline (783.665 us; speedup 1.0000x reference)
//
#include <hip/hip_runtime.h>

#define EPS 1e-5f

// ---------------- degree / dinv ----------------

__global__ void k_init_deg(float* __restrict__ deg, int n) {
    int i = blockIdx.x * blockDim.x + threadIdx.x;
    if (i < n) deg[i] = 1.0f;  // self-loop
}

__global__ void k_count_deg(const int* __restrict__ col, float* __restrict__ deg, int e) {
    int i = blockIdx.x * blockDim.x + threadIdx.x;
    if (i < e) atomicAdd(&deg[col[i]], 1.0f);
}

__global__ void k_dinv(float* __restrict__ deg, int n) {
    int i = blockIdx.x * blockDim.x + threadIdx.x;
    if (i < n) deg[i] = rsqrtf(deg[i]);  // deg >= 1 always (self-loop)
}

// ---------------- input MLP: h = relu(x @ W_in + b_in) ----------------
// one wave per node; lane = output feature (64)

__global__ void k_input_mlp(const float* __restrict__ x, const float* __restrict__ Win,
                            const float* __restrict__ bin, float* __restrict__ h, int n) {
    int wave = threadIdx.x >> 6;
    int lane = threadIdx.x & 63;
    int node = blockIdx.x * 4 + wave;
    if (node >= n) return;
    float acc = bin[lane];
    const float* xr = x + (size_t)node * 16;
#pragma unroll
    for (int k = 0; k < 16; ++k) {
        acc += xr[k] * Win[k * 64 + lane];  // xr[k]: wave-uniform broadcast load
    }
    h[(size_t)node * 64 + lane] = fmaxf(acc, 0.0f);
}

// ---------------- transform + self-loop/bias init ----------------
// t = h @ Wc ; agg = t * dinv^2 + b_conv
// one wave per node; lane = output feature. h row broadcast via LDS.

__global__ void k_transform_init(const float* __restrict__ h, const float* __restrict__ Wc,
                                 const float* __restrict__ bc, const float* __restrict__ dinv,
                                 float* __restrict__ t, float* __restrict__ agg, int n) {
    __shared__ float sh[4][64];
    int wave = threadIdx.x >> 6;
    int lane = threadIdx.x & 63;
    int node = blockIdx.x * 4 + wave;
    if (node >= n) return;
    sh[wave][lane] = h[(size_t)node * 64 + lane];
    // same-wave LDS write->read: lockstep, compiler inserts lgkmcnt wait
    float acc = 0.0f;
#pragma unroll
    for (int k = 0; k < 64; ++k) {
        acc += sh[wave][k] * Wc[k * 64 + lane];  // sh[wave][k] broadcast, Wc coalesced
    }
    size_t idx = (size_t)node * 64 + lane;
    t[idx] = acc;
    float dv = dinv[node];
    agg[idx] = acc * dv * dv + bc[lane];
}

// ---------------- edge scatter: agg[col] += t[row] * dinv[row]*dinv[col] ----------------
// one wave per edge; lane = feature

__global__ void k_scatter(const int* __restrict__ row, const int* __restrict__ col,
                          const float* __restrict__ dinv, const float* __restrict__ t,
                          float* __restrict__ agg, int e) {
    int wave = threadIdx.x >> 6;
    int lane = threadIdx.x & 63;
    int ed = blockIdx.x * 4 + wave;
    if (ed >= e) return;
    int r = row[ed];
    int c = col[ed];
    float w = dinv[r] * dinv[c];
    float v = t[(size_t)r * 64 + lane] * w;
    atomicAdd(&agg[(size_t)c * 64 + lane], v);
}

// ---------------- layernorm + relu + residual ----------------
// h = relu(LN(agg)*gamma+beta) + h

__global__ void k_ln_relu_res(const float* __restrict__ agg, const float* __restrict__ gamma,
                              const float* __restrict__ beta, float* __restrict__ h, int n) {
    int wave = threadIdx.x >> 6;
    int lane = threadIdx.x & 63;
    int node = blockIdx.x * 4 + wave;
    if (node >= n) return;
    size_t idx = (size_t)node * 64 + lane;
    float v = agg[idx];
    float s = v;
#pragma unroll
    for (int off = 32; off; off >>= 1) s += __shfl_xor(s, off);
    float mu = s * (1.0f / 64.0f);
    float d = v - mu;
    float q = d * d;
#pragma unroll
    for (int off = 32; off; off >>= 1) q += __shfl_xor(q, off);
    float var = q * (1.0f / 64.0f);
    float y = d * rsqrtf(var + EPS) * gamma[lane] + beta[lane];
    y = fmaxf(y, 0.0f);
    h[idx] = y + h[idx];
}

// ---------------- output head: out = h @ W_out + b_out ----------------

__global__ void k_out(const float* __restrict__ h, const float* __restrict__ Wout,
                      const float* __restrict__ bout, float* __restrict__ out, int n) {
    int wave = threadIdx.x >> 6;
    int lane = threadIdx.x & 63;
    int node = blockIdx.x * 4 + wave;
    if (node >= n) return;
    float v = h[(size_t)node * 64 + lane] * Wout[lane];
#pragma unroll
    for (int off = 32; off; off >>= 1) v += __shfl_xor(v, off);
    if (lane == 0) out[node] = v + bout[0];
}

extern "C" void kernel_launch(void* const* d_in, const int* in_sizes, int n_in,
                              void* d_out, int out_size, void* d_ws, size_t ws_size,
                              hipStream_t stream) {
    const float* x     = (const float*)d_in[0];
    const int*   eidx  = (const int*)d_in[1];
    const float* Win   = (const float*)d_in[2];
    const float* bin   = (const float*)d_in[3];
    const float* Wconv = (const float*)d_in[4];
    const float* bconv = (const float*)d_in[5];
    const float* gamma = (const float*)d_in[6];
    const float* beta  = (const float*)d_in[7];
    const float* Wout  = (const float*)d_in[8];
    const float* bout  = (const float*)d_in[9];
    float* out = (float*)d_out;

    const int N = in_sizes[0] / 16;       // 50000
    const int E = in_sizes[1] / 2;        // 800000
    const int L = in_sizes[4] / (64 * 64); // 3

    const int* row = eidx;
    const int* col = eidx + E;

    // workspace layout (16B-aligned)
    char* ws = (char*)d_ws;
    size_t off = 0;
    auto alloc = [&](size_t bytes) {
        size_t p = off;
        off += (bytes + 255) & ~(size_t)255;
        return (float*)(ws + p);
    };
    float* dinv = alloc((size_t)N * 4);
    float* h    = alloc((size_t)N * 64 * 4);
    float* t    = alloc((size_t)N * 64 * 4);
    float* agg  = alloc((size_t)N * 64 * 4);
    (void)ws_size;

    const int BT = 256;
    int gN1   = (N + BT - 1) / BT;       // 1 node/thread
    int gE1   = (E + BT - 1) / BT;       // 1 edge/thread
    int gN64  = (N + 3) / 4;             // 1 node/wave, 4 waves/block
    int gE64  = (E + 3) / 4;             // 1 edge/wave

    k_init_deg<<<gN1, BT, 0, stream>>>(dinv, N);
    k_count_deg<<<gE1, BT, 0, stream>>>(col, dinv, E);
    k_dinv<<<gN1, BT, 0, stream>>>(dinv, N);

    k_input_mlp<<<gN64, BT, 0, stream>>>(x, Win, bin, h, N);

    for (int l = 0; l < L; ++l) {
        const float* Wc = Wconv + (size_t)l * 64 * 64;
        const float* bc = bconv + (size_t)l * 64;
        const float* gm = gamma + (size_t)l * 64;
        const float* bt = beta + (size_t)l * 64;
        k_transform_init<<<gN64, BT, 0, stream>>>(h, Wc, bc, dinv, t, agg, N);
        k_scatter<<<gE64, BT, 0, stream>>>(row, col, dinv, t, agg, E);
        k_ln_relu_res<<<gN64, BT, 0, stream>>>(agg, gm, bt, h, N);
    }

    k_out<<<gN64, BT, 0, stream>>>(h, Wout, bout, out, N);
}

// Round 2
// 435.901 us; speedup vs baseline: 1.7978x; 1.7978x over previous
//
#include <hip/hip_runtime.h>

#define EPS 1e-5f

// ================= bucket build (counting sort of edges by destination) =======

__global__ void k_zero(int* __restrict__ cnt, int n) {
    int i = blockIdx.x * blockDim.x + threadIdx.x;
    if (i < n) cnt[i] = 0;
}

__global__ void k_hist(const int* __restrict__ col, int* __restrict__ cnt, int e) {
    int i = blockIdx.x * blockDim.x + threadIdx.x;
    if (i < e) atomicAdd(&cnt[col[i]], 1);
}

// single-block exclusive scan over cnt[0..n) -> start, cursor; also dinv = rsqrt(cnt+1)
__global__ void k_scan(const int* __restrict__ cnt, int* __restrict__ start,
                       int* __restrict__ cursor, float* __restrict__ dinv, int n) {
    __shared__ int wsum[16];
    int tid = threadIdx.x;
    int lane = tid & 63, wv = tid >> 6;
    int carry = 0;
    for (int base = 0; base < n; base += 1024) {
        int i = base + tid;
        int v = (i < n) ? cnt[i] : 0;
        int x = v;
#pragma unroll
        for (int off = 1; off < 64; off <<= 1) {
            int y = __shfl_up(x, off);
            if (lane >= off) x += y;
        }
        if (lane == 63) wsum[wv] = x;
        __syncthreads();
        if (wv == 0 && lane < 16) {
            int w = wsum[lane];
#pragma unroll
            for (int off = 1; off < 16; off <<= 1) {
                int y = __shfl_up(w, off);
                if (lane >= off) w += y;
            }
            wsum[lane] = w;  // inclusive over wave totals
        }
        __syncthreads();
        int wofs = (wv == 0) ? 0 : wsum[wv - 1];
        int excl = carry + wofs + (x - v);
        if (i < n) {
            start[i] = excl;
            cursor[i] = excl;
            dinv[i] = rsqrtf((float)(v + 1));  // +1 self-loop
        }
        carry += wsum[15];
        __syncthreads();
    }
    if (tid == 0) start[n] = carry;
}

__global__ void k_bucket(const int* __restrict__ row, const int* __restrict__ col,
                         int* __restrict__ cursor, int* __restrict__ bRow, int e) {
    int i = blockIdx.x * blockDim.x + threadIdx.x;
    if (i < e) {
        int pos = atomicAdd(&cursor[col[i]], 1);
        bRow[pos] = row[i];
    }
}

// ================= fused input MLP + layer-0 transform ========================
// h = relu(x@Win+bin); ts = (h@Wc) * dinv   (one wave per node, lane = feature)

__global__ void k_mlp_transform(const float* __restrict__ x, const float* __restrict__ Win,
                                const float* __restrict__ bin, const float* __restrict__ Wc,
                                const float* __restrict__ dinv, float* __restrict__ h,
                                float* __restrict__ ts, int n) {
    int wv = threadIdx.x >> 6, lane = threadIdx.x & 63;
    int node = blockIdx.x * 4 + wv;
    if (node >= n) return;
    float a = bin[lane];
    const float* xr = x + (size_t)node * 16;
#pragma unroll
    for (int k = 0; k < 16; ++k) a += xr[k] * Win[k * 64 + lane];
    a = fmaxf(a, 0.0f);
    size_t idx = (size_t)node * 64 + lane;
    h[idx] = a;
    float acc = 0.0f;
#pragma unroll
    for (int k = 0; k < 64; ++k) acc += __shfl(a, k) * Wc[k * 64 + lane];
    ts[idx] = acc * dinv[node];
}

// ================= transform (layers 1,2): ts = (h@Wc) * dinv =================

__global__ void k_transform(const float* __restrict__ h, const float* __restrict__ Wc,
                            const float* __restrict__ dinv, float* __restrict__ ts, int n) {
    int wv = threadIdx.x >> 6, lane = threadIdx.x & 63;
    int node = blockIdx.x * 4 + wv;
    if (node >= n) return;
    size_t idx = (size_t)node * 64 + lane;
    float a = h[idx];
    float acc = 0.0f;
#pragma unroll
    for (int k = 0; k < 64; ++k) acc += __shfl(a, k) * Wc[k * 64 + lane];
    ts[idx] = acc * dinv[node];
}

// ====== gather + LN + relu + residual (+ optional output head, last layer) ====
// agg = dinv[c]*(sum_{r in in(c)} ts[r] + ts[c]) + bc ; h = relu(LN(agg)) + h

__global__ void k_gather(const int* __restrict__ start, const int* __restrict__ bRow,
                         const float* __restrict__ ts, const float* __restrict__ dinv,
                         const float* __restrict__ bc, const float* __restrict__ gm,
                         const float* __restrict__ bt, float* __restrict__ h, int n,
                         const float* __restrict__ Wout, const float* __restrict__ bout,
                         float* __restrict__ out, int do_out) {
    int wv = threadIdx.x >> 6, lane = threadIdx.x & 63;
    int node = blockIdx.x * 4 + wv;
    if (node >= n) return;
    int e0 = start[node], e1 = start[node + 1];
    float a0 = 0.f, a1 = 0.f, a2 = 0.f, a3 = 0.f;
    for (int e = e0; e < e1; e += 64) {
        int cnt = min(64, e1 - e);
        int r = bRow[e + ((lane < cnt) ? lane : 0)];
        int j = 0;
        for (; j + 3 < cnt; j += 4) {
            int r0 = __shfl(r, j), r1 = __shfl(r, j + 1);
            int r2 = __shfl(r, j + 2), r3 = __shfl(r, j + 3);
            a0 += ts[(size_t)r0 * 64 + lane];
            a1 += ts[(size_t)r1 * 64 + lane];
            a2 += ts[(size_t)r2 * 64 + lane];
            a3 += ts[(size_t)r3 * 64 + lane];
        }
        for (; j < cnt; ++j) {
            int rj = __shfl(r, j);
            a0 += ts[(size_t)rj * 64 + lane];
        }
    }
    float acc = (a0 + a1) + (a2 + a3);
    size_t idx = (size_t)node * 64 + lane;
    float v = (acc + ts[idx]) * dinv[node] + bc[lane];
    // layernorm over 64 lanes
    float s = v;
#pragma unroll
    for (int off = 32; off; off >>= 1) s += __shfl_xor(s, off);
    float mu = s * (1.0f / 64.0f);
    float d = v - mu;
    float q = d * d;
#pragma unroll
    for (int off = 32; off; off >>= 1) q += __shfl_xor(q, off);
    float y = d * rsqrtf(q * (1.0f / 64.0f) + EPS) * gm[lane] + bt[lane];
    y = fmaxf(y, 0.0f) + h[idx];
    h[idx] = y;
    if (do_out) {
        float o = y * Wout[lane];
#pragma unroll
        for (int off = 32; off; off >>= 1) o += __shfl_xor(o, off);
        if (lane == 0) out[node] = o + bout[0];
    }
}

extern "C" void kernel_launch(void* const* d_in, const int* in_sizes, int n_in,
                              void* d_out, int out_size, void* d_ws, size_t ws_size,
                              hipStream_t stream) {
    const float* x     = (const float*)d_in[0];
    const int*   eidx  = (const int*)d_in[1];
    const float* Win   = (const float*)d_in[2];
    const float* bin   = (const float*)d_in[3];
    const float* Wconv = (const float*)d_in[4];
    const float* bconv = (const float*)d_in[5];
    const float* gamma = (const float*)d_in[6];
    const float* beta  = (const float*)d_in[7];
    const float* Wout  = (const float*)d_in[8];
    const float* bout  = (const float*)d_in[9];
    float* out = (float*)d_out;

    const int N = in_sizes[0] / 16;
    const int E = in_sizes[1] / 2;
    const int L = in_sizes[4] / (64 * 64);

    const int* row = eidx;
    const int* col = eidx + E;

    char* ws = (char*)d_ws;
    size_t off = 0;
    auto alloc = [&](size_t bytes) -> void* {
        size_t p = off;
        off += (bytes + 255) & ~(size_t)255;
        return (void*)(ws + p);
    };
    float* dinv   = (float*)alloc((size_t)N * 4);
    int*   cnt    = (int*)alloc((size_t)N * 4);
    int*   startA = (int*)alloc((size_t)(N + 1) * 4);
    int*   cursor = (int*)alloc((size_t)N * 4);
    int*   bRow   = (int*)alloc((size_t)E * 4);
    float* h      = (float*)alloc((size_t)N * 64 * 4);
    float* ts     = (float*)alloc((size_t)N * 64 * 4);
    (void)ws_size;

    const int BT = 256;
    int gN1  = (N + BT - 1) / BT;
    int gE1  = (E + BT - 1) / BT;
    int gN64 = (N + 3) / 4;

    k_zero<<<gN1, BT, 0, stream>>>(cnt, N);
    k_hist<<<gE1, BT, 0, stream>>>(col, cnt, E);
    k_scan<<<1, 1024, 0, stream>>>(cnt, startA, cursor, dinv, N);
    k_bucket<<<gE1, BT, 0, stream>>>(row, col, cursor, bRow, E);

    k_mlp_transform<<<gN64, BT, 0, stream>>>(x, Win, bin, Wconv, dinv, h, ts, N);

    for (int l = 0; l < L; ++l) {
        const float* bc = bconv + (size_t)l * 64;
        const float* gm = gamma + (size_t)l * 64;
        const float* bt = beta + (size_t)l * 64;
        int last = (l == L - 1);
        k_gather<<<gN64, BT, 0, stream>>>(startA, bRow, ts, dinv, bc, gm, bt, h, N,
                                          Wout, bout, out, last);
        if (!last) {
            const float* Wc = Wconv + (size_t)(l + 1) * 64 * 64;
            k_transform<<<gN64, BT, 0, stream>>>(h, Wc, dinv, ts, N);
        }
    }
}

// Round 3
// 322.813 us; speedup vs baseline: 2.4276x; 1.3503x over previous
//
#include <hip/hip_runtime.h>

#define EPS 1e-5f
#define CPAD 16  // cnt padded to one int per 64B line

// ============== CSR build: hist(+rank) -> 3-phase scan -> bucket =============

__global__ void k_hist_rank(const int* __restrict__ col, int* __restrict__ cnt,
                            unsigned short* __restrict__ rank, int e) {
    int i = blockIdx.x * blockDim.x + threadIdx.x;
    if (i < e) {
        int old = atomicAdd(&cnt[(size_t)col[i] * CPAD], 1);
        rank[i] = (unsigned short)old;
    }
}

// per-block sums of 256-element chunks of cnt
__global__ void k_scan_blocks(const int* __restrict__ cnt, int* __restrict__ bsum, int n) {
    __shared__ int ws[4];
    int t = threadIdx.x, lane = t & 63, wv = t >> 6;
    int i = blockIdx.x * 256 + t;
    int v = (i < n) ? cnt[(size_t)i * CPAD] : 0;
    int x = v;
#pragma unroll
    for (int off = 32; off; off >>= 1) x += __shfl_xor(x, off);
    if (lane == 0) ws[wv] = x;
    __syncthreads();
    if (t == 0) bsum[blockIdx.x] = ws[0] + ws[1] + ws[2] + ws[3];
}

// single block scans the (<=1024) block sums -> exclusive bofs; start[n]=total
__global__ void k_scan_top(const int* __restrict__ bsum, int* __restrict__ bofs,
                           int* __restrict__ start, int nb, int n) {
    __shared__ int s[1024];
    int t = threadIdx.x;
    int v = (t < nb) ? bsum[t] : 0;
    s[t] = v;
    __syncthreads();
    for (int off = 1; off < 1024; off <<= 1) {
        int y = (t >= off) ? s[t - off] : 0;
        __syncthreads();
        s[t] += y;
        __syncthreads();
    }
    if (t < nb) bofs[t] = s[t] - v;      // exclusive
    if (t == nb - 1) start[n] = s[t];    // grand total
}

// block-local scan + block offset -> start[i]; also dinv = rsqrt(cnt+1)
__global__ void k_scan_apply(const int* __restrict__ cnt, const int* __restrict__ bofs,
                             int* __restrict__ start, float* __restrict__ dinv, int n) {
    __shared__ int ws[4];
    int t = threadIdx.x, lane = t & 63, wv = t >> 6;
    int i = blockIdx.x * 256 + t;
    int v = (i < n) ? cnt[(size_t)i * CPAD] : 0;
    int x = v;
#pragma unroll
    for (int off = 1; off < 64; off <<= 1) {
        int y = __shfl_up(x, off);
        if (lane >= off) x += y;
    }
    if (lane == 63) ws[wv] = x;
    __syncthreads();
    int wofs = 0;
#pragma unroll
    for (int w = 0; w < 4; ++w) wofs += (w < wv) ? ws[w] : 0;
    if (i < n) {
        start[i] = bofs[blockIdx.x] + wofs + (x - v);
        dinv[i] = rsqrtf((float)(v + 1));
    }
}

__global__ void k_bucket(const int* __restrict__ row, const int* __restrict__ col,
                         const int* __restrict__ start, const unsigned short* __restrict__ rank,
                         int* __restrict__ bRow, int e) {
    int i = blockIdx.x * blockDim.x + threadIdx.x;
    if (i < e) bRow[start[col[i]] + (int)rank[i]] = row[i];
}

// ============== fused input MLP + layer-0 transform ==========================
// h = relu(x@Win+bin); ts = (h@Wc0) * dinv   (one wave/node, lane = feature)

__global__ void k_mlp_transform(const float* __restrict__ x, const float* __restrict__ Win,
                                const float* __restrict__ bin, const float* __restrict__ Wc,
                                const float* __restrict__ dinv, float* __restrict__ h,
                                float* __restrict__ ts, int n) {
    int wv = threadIdx.x >> 6, lane = threadIdx.x & 63;
    int node = blockIdx.x * 4 + wv;
    if (node >= n) return;
    float a = bin[lane];
    const float* xr = x + (size_t)node * 16;
#pragma unroll
    for (int k = 0; k < 16; ++k) a += xr[k] * Win[k * 64 + lane];
    a = fmaxf(a, 0.0f);
    size_t idx = (size_t)node * 64 + lane;
    h[idx] = a;
    float acc = 0.0f;
#pragma unroll
    for (int k = 0; k < 64; ++k) acc += __shfl(a, k) * Wc[k * 64 + lane];
    ts[idx] = acc * dinv[node];
}

// ====== gather + LN + relu + residual + fused next-transform / output head ===
// v   = dinv[c]*(sum_{r in in(c)} ts[r] + ts[c]) + bc
// y   = relu(LN(v)*gm+bt) + h ;  h = y
// if do_next: ts_out = (y @ Wc_next) * dinv
// if do_out:  out = y @ Wout + bout

__global__ void k_gather(const int* __restrict__ start, const int* __restrict__ bRow,
                         const float* __restrict__ ts, const float* __restrict__ dinv,
                         const float* __restrict__ bc, const float* __restrict__ gm,
                         const float* __restrict__ bt, float* __restrict__ h, int n,
                         const float* __restrict__ WcN, float* __restrict__ tsOut, int do_next,
                         const float* __restrict__ Wout, const float* __restrict__ bout,
                         float* __restrict__ out, int do_out) {
    int wv = threadIdx.x >> 6, lane = threadIdx.x & 63;
    int node = blockIdx.x * 4 + wv;
    if (node >= n) return;
    int e0 = start[node], e1 = start[node + 1];
    float a0 = 0.f, a1 = 0.f, a2 = 0.f, a3 = 0.f;
    for (int e = e0; e < e1; e += 64) {
        int cnt = min(64, e1 - e);
        int r = bRow[e + ((lane < cnt) ? lane : 0)];
        int j = 0;
        for (; j + 3 < cnt; j += 4) {
            int r0 = __shfl(r, j), r1 = __shfl(r, j + 1);
            int r2 = __shfl(r, j + 2), r3 = __shfl(r, j + 3);
            a0 += ts[(size_t)r0 * 64 + lane];
            a1 += ts[(size_t)r1 * 64 + lane];
            a2 += ts[(size_t)r2 * 64 + lane];
            a3 += ts[(size_t)r3 * 64 + lane];
        }
        for (; j < cnt; ++j) {
            int rj = __shfl(r, j);
            a0 += ts[(size_t)rj * 64 + lane];
        }
    }
    float acc = (a0 + a1) + (a2 + a3);
    size_t idx = (size_t)node * 64 + lane;
    float dv = dinv[node];
    float v = (acc + ts[idx]) * dv + bc[lane];
    // layernorm over the 64-lane feature dim
    float s = v;
#pragma unroll
    for (int off = 32; off; off >>= 1) s += __shfl_xor(s, off);
    float mu = s * (1.0f / 64.0f);
    float d = v - mu;
    float q = d * d;
#pragma unroll
    for (int off = 32; off; off >>= 1) q += __shfl_xor(q, off);
    float y = d * rsqrtf(q * (1.0f / 64.0f) + EPS) * gm[lane] + bt[lane];
    y = fmaxf(y, 0.0f) + h[idx];
    h[idx] = y;
    if (do_next) {
        float acc2 = 0.0f;
#pragma unroll
        for (int k = 0; k < 64; ++k) acc2 += __shfl(y, k) * WcN[k * 64 + lane];
        tsOut[idx] = acc2 * dv;
    }
    if (do_out) {
        float o = y * Wout[lane];
#pragma unroll
        for (int off = 32; off; off >>= 1) o += __shfl_xor(o, off);
        if (lane == 0) out[node] = o + bout[0];
    }
}

extern "C" void kernel_launch(void* const* d_in, const int* in_sizes, int n_in,
                              void* d_out, int out_size, void* d_ws, size_t ws_size,
                              hipStream_t stream) {
    const float* x     = (const float*)d_in[0];
    const int*   eidx  = (const int*)d_in[1];
    const float* Win   = (const float*)d_in[2];
    const float* bin   = (const float*)d_in[3];
    const float* Wconv = (const float*)d_in[4];
    const float* bconv = (const float*)d_in[5];
    const float* gamma = (const float*)d_in[6];
    const float* beta  = (const float*)d_in[7];
    const float* Wout  = (const float*)d_in[8];
    const float* bout  = (const float*)d_in[9];
    float* out = (float*)d_out;

    const int N = in_sizes[0] / 16;
    const int E = in_sizes[1] / 2;
    const int L = in_sizes[4] / (64 * 64);

    const int* row = eidx;
    const int* col = eidx + E;

    char* ws = (char*)d_ws;
    size_t off = 0;
    auto alloc = [&](size_t bytes) -> void* {
        size_t p = off;
        off += (bytes + 255) & ~(size_t)255;
        return (void*)(ws + p);
    };
    int*   cnt    = (int*)alloc((size_t)N * CPAD * 4);
    unsigned short* rank = (unsigned short*)alloc((size_t)E * 2);
    int*   bsum   = (int*)alloc(1024 * 4);
    int*   bofs   = (int*)alloc(1024 * 4);
    int*   startA = (int*)alloc((size_t)(N + 1) * 4);
    float* dinv   = (float*)alloc((size_t)N * 4);
    int*   bRow   = (int*)alloc((size_t)E * 4);
    float* h      = (float*)alloc((size_t)N * 64 * 4);
    float* tsA    = (float*)alloc((size_t)N * 64 * 4);
    float* tsB    = (float*)alloc((size_t)N * 64 * 4);
    (void)ws_size;

    const int BT = 256;
    int gE1  = (E + BT - 1) / BT;
    int gN64 = (N + 3) / 4;
    int nb   = (N + 255) / 256;  // scan blocks (<=1024)

    hipMemsetAsync(cnt, 0, (size_t)N * CPAD * 4, stream);
    k_hist_rank<<<gE1, BT, 0, stream>>>(col, cnt, rank, E);
    k_scan_blocks<<<nb, 256, 0, stream>>>(cnt, bsum, N);
    k_scan_top<<<1, 1024, 0, stream>>>(bsum, bofs, startA, nb, N);
    k_scan_apply<<<nb, 256, 0, stream>>>(cnt, bofs, startA, dinv, N);
    k_bucket<<<gE1, BT, 0, stream>>>(row, col, startA, rank, bRow, E);

    k_mlp_transform<<<gN64, BT, 0, stream>>>(x, Win, bin, Wconv, dinv, h, tsA, N);

    float* bufs[2] = {tsA, tsB};
    for (int l = 0; l < L; ++l) {
        const float* bc = bconv + (size_t)l * 64;
        const float* gm = gamma + (size_t)l * 64;
        const float* bt = beta + (size_t)l * 64;
        int last = (l == L - 1);
        const float* WcN = last ? Wconv : Wconv + (size_t)(l + 1) * 64 * 64;
        k_gather<<<gN64, BT, 0, stream>>>(startA, bRow, bufs[l & 1], dinv, bc, gm, bt, h, N,
                                          WcN, bufs[(l + 1) & 1], !last,
                                          Wout, bout, out, last);
    }
}

// Round 4
// 314.742 us; speedup vs baseline: 2.4899x; 1.0256x over previous
//
#include <hip/hip_runtime.h>
#include <hip/hip_fp16.h>

#define EPS 1e-5f
#define CPAD 16  // cnt padded to one int per 64B line

// ============== CSR build: hist(+rank) -> 3-phase scan -> bucket =============

__global__ void k_hist_rank(const int* __restrict__ col, int* __restrict__ cnt,
                            unsigned short* __restrict__ rank, int e) {
    int i = blockIdx.x * blockDim.x + threadIdx.x;
    if (i < e) {
        int old = atomicAdd(&cnt[(size_t)col[i] * CPAD], 1);
        rank[i] = (unsigned short)old;
    }
}

__global__ void k_scan_blocks(const int* __restrict__ cnt, int* __restrict__ bsum, int n) {
    __shared__ int ws[4];
    int t = threadIdx.x, lane = t & 63, wv = t >> 6;
    int i = blockIdx.x * 256 + t;
    int v = (i < n) ? cnt[(size_t)i * CPAD] : 0;
    int x = v;
#pragma unroll
    for (int off = 32; off; off >>= 1) x += __shfl_xor(x, off);
    if (lane == 0) ws[wv] = x;
    __syncthreads();
    if (t == 0) bsum[blockIdx.x] = ws[0] + ws[1] + ws[2] + ws[3];
}

__global__ void k_scan_top(const int* __restrict__ bsum, int* __restrict__ bofs,
                           int* __restrict__ start, int nb, int n) {
    __shared__ int s[1024];
    int t = threadIdx.x;
    int v = (t < nb) ? bsum[t] : 0;
    s[t] = v;
    __syncthreads();
    for (int off = 1; off < 1024; off <<= 1) {
        int y = (t >= off) ? s[t - off] : 0;
        __syncthreads();
        s[t] += y;
        __syncthreads();
    }
    if (t < nb) bofs[t] = s[t] - v;      // exclusive
    if (t == nb - 1) start[n] = s[t];    // grand total
}

__global__ void k_scan_apply(const int* __restrict__ cnt, const int* __restrict__ bofs,
                             int* __restrict__ start, float* __restrict__ dinv, int n) {
    __shared__ int ws[4];
    int t = threadIdx.x, lane = t & 63, wv = t >> 6;
    int i = blockIdx.x * 256 + t;
    int v = (i < n) ? cnt[(size_t)i * CPAD] : 0;
    int x = v;
#pragma unroll
    for (int off = 1; off < 64; off <<= 1) {
        int y = __shfl_up(x, off);
        if (lane >= off) x += y;
    }
    if (lane == 63) ws[wv] = x;
    __syncthreads();
    int wofs = 0;
#pragma unroll
    for (int w = 0; w < 4; ++w) wofs += (w < wv) ? ws[w] : 0;
    if (i < n) {
        start[i] = bofs[blockIdx.x] + wofs + (x - v);
        dinv[i] = rsqrtf((float)(v + 1));
    }
}

__global__ void k_bucket(const int* __restrict__ row, const int* __restrict__ col,
                         const int* __restrict__ start, const unsigned short* __restrict__ rank,
                         int* __restrict__ bRow, int e) {
    int i = blockIdx.x * blockDim.x + threadIdx.x;
    if (i < e) bRow[start[col[i]] + (int)rank[i]] = row[i];
}

// ============== fused input MLP + layer-0 transform ==========================
// h = relu(x@Win+bin); ts = fp16((h@Wc0) * dinv)   (one wave/node, lane = feat)

__global__ void k_mlp_transform(const float* __restrict__ x, const float* __restrict__ Win,
                                const float* __restrict__ bin, const float* __restrict__ Wc,
                                const float* __restrict__ dinv, float* __restrict__ h,
                                __half* __restrict__ ts, int n) {
    int wv = threadIdx.x >> 6, lane = threadIdx.x & 63;
    int node = blockIdx.x * 4 + wv;
    if (node >= n) return;
    float a = bin[lane];
    const float* xr = x + (size_t)node * 16;
#pragma unroll
    for (int k = 0; k < 16; ++k) a += xr[k] * Win[k * 64 + lane];
    a = fmaxf(a, 0.0f);
    size_t idx = (size_t)node * 64 + lane;
    h[idx] = a;
    float acc = 0.0f;
#pragma unroll
    for (int k = 0; k < 64; ++k) acc += __shfl(a, k) * Wc[k * 64 + lane];
    ts[idx] = __float2half(acc * dinv[node]);
}

// ====== gather + LN + relu + residual + fused next-transform / output head ===

__global__ void k_gather(const int* __restrict__ start, const int* __restrict__ bRow,
                         const __half* __restrict__ ts, const float* __restrict__ dinv,
                         const float* __restrict__ bc, const float* __restrict__ gm,
                         const float* __restrict__ bt, float* __restrict__ h, int n,
                         const float* __restrict__ WcN, __half* __restrict__ tsOut, int do_next,
                         const float* __restrict__ Wout, const float* __restrict__ bout,
                         float* __restrict__ out, int do_out) {
    int wv = threadIdx.x >> 6, lane = threadIdx.x & 63;
    int node = blockIdx.x * 4 + wv;
    if (node >= n) return;
    int e0 = start[node], e1 = start[node + 1];
    float a0 = 0.f, a1 = 0.f, a2 = 0.f, a3 = 0.f;
    for (int e = e0; e < e1; e += 64) {
        int cnt = min(64, e1 - e);
        int r = bRow[e + ((lane < cnt) ? lane : 0)];
        int j = 0;
        for (; j + 3 < cnt; j += 4) {
            int r0 = __shfl(r, j), r1 = __shfl(r, j + 1);
            int r2 = __shfl(r, j + 2), r3 = __shfl(r, j + 3);
            a0 += __half2float(ts[(size_t)r0 * 64 + lane]);
            a1 += __half2float(ts[(size_t)r1 * 64 + lane]);
            a2 += __half2float(ts[(size_t)r2 * 64 + lane]);
            a3 += __half2float(ts[(size_t)r3 * 64 + lane]);
        }
        for (; j < cnt; ++j) {
            int rj = __shfl(r, j);
            a0 += __half2float(ts[(size_t)rj * 64 + lane]);
        }
    }
    float acc = (a0 + a1) + (a2 + a3);
    size_t idx = (size_t)node * 64 + lane;
    float dv = dinv[node];
    float v = (acc + __half2float(ts[idx])) * dv + bc[lane];
    // layernorm over the 64-lane feature dim
    float s = v;
#pragma unroll
    for (int off = 32; off; off >>= 1) s += __shfl_xor(s, off);
    float mu = s * (1.0f / 64.0f);
    float d = v - mu;
    float q = d * d;
#pragma unroll
    for (int off = 32; off; off >>= 1) q += __shfl_xor(q, off);
    float y = d * rsqrtf(q * (1.0f / 64.0f) + EPS) * gm[lane] + bt[lane];
    y = fmaxf(y, 0.0f) + h[idx];
    h[idx] = y;
    if (do_next) {
        float acc2 = 0.0f;
#pragma unroll
        for (int k = 0; k < 64; ++k) acc2 += __shfl(y, k) * WcN[k * 64 + lane];
        tsOut[idx] = __float2half(acc2 * dv);
    }
    if (do_out) {
        float o = y * Wout[lane];
#pragma unroll
        for (int off = 32; off; off >>= 1) o += __shfl_xor(o, off);
        if (lane == 0) out[node] = o + bout[0];
    }
}

extern "C" void kernel_launch(void* const* d_in, const int* in_sizes, int n_in,
                              void* d_out, int out_size, void* d_ws, size_t ws_size,
                              hipStream_t stream) {
    const float* x     = (const float*)d_in[0];
    const int*   eidx  = (const int*)d_in[1];
    const float* Win   = (const float*)d_in[2];
    const float* bin   = (const float*)d_in[3];
    const float* Wconv = (const float*)d_in[4];
    const float* bconv = (const float*)d_in[5];
    const float* gamma = (const float*)d_in[6];
    const float* beta  = (const float*)d_in[7];
    const float* Wout  = (const float*)d_in[8];
    const float* bout  = (const float*)d_in[9];
    float* out = (float*)d_out;

    const int N = in_sizes[0] / 16;
    const int E = in_sizes[1] / 2;
    const int L = in_sizes[4] / (64 * 64);

    const int* row = eidx;
    const int* col = eidx + E;

    char* ws = (char*)d_ws;
    size_t off = 0;
    auto alloc = [&](size_t bytes) -> void* {
        size_t p = off;
        off += (bytes + 255) & ~(size_t)255;
        return (void*)(ws + p);
    };
    int*   cnt    = (int*)alloc((size_t)N * CPAD * 4);
    unsigned short* rank = (unsigned short*)alloc((size_t)E * 2);
    int*   bsum   = (int*)alloc(1024 * 4);
    int*   bofs   = (int*)alloc(1024 * 4);
    int*   startA = (int*)alloc((size_t)(N + 1) * 4);
    float* dinv   = (float*)alloc((size_t)N * 4);
    int*   bRow   = (int*)alloc((size_t)E * 4);
    float* h      = (float*)alloc((size_t)N * 64 * 4);
    __half* tsA   = (__half*)alloc((size_t)N * 64 * 2);
    __half* tsB   = (__half*)alloc((size_t)N * 64 * 2);
    (void)ws_size;

    const int BT = 256;
    int gE1  = (E + BT - 1) / BT;
    int gN64 = (N + 3) / 4;
    int nb   = (N + 255) / 256;  // scan blocks (<=1024)

    hipMemsetAsync(cnt, 0, (size_t)N * CPAD * 4, stream);
    k_hist_rank<<<gE1, BT, 0, stream>>>(col, cnt, rank, E);
    k_scan_blocks<<<nb, 256, 0, stream>>>(cnt, bsum, N);
    k_scan_top<<<1, 1024, 0, stream>>>(bsum, bofs, startA, nb, N);
    k_scan_apply<<<nb, 256, 0, stream>>>(cnt, bofs, startA, dinv, N);
    k_bucket<<<gE1, BT, 0, stream>>>(row, col, startA, rank, bRow, E);

    k_mlp_transform<<<gN64, BT, 0, stream>>>(x, Win, bin, Wconv, dinv, h, tsA, N);

    __half* bufs[2] = {tsA, tsB};
    for (int l = 0; l < L; ++l) {
        const float* bc = bconv + (size_t)l * 64;
        const float* gm = gamma + (size_t)l * 64;
        const float* bt = beta + (size_t)l * 64;
        int last = (l == L - 1);
        const float* WcN = last ? Wconv : Wconv + (size_t)(l + 1) * 64 * 64;
        k_gather<<<gN64, BT, 0, stream>>>(startA, bRow, bufs[l & 1], dinv, bc, gm, bt, h, N,
                                          WcN, bufs[(l + 1) & 1], !last,
                                          Wout, bout, out, last);
    }
}

// Round 5
// 307.358 us; speedup vs baseline: 2.5497x; 1.0240x over previous
//
#include <hip/hip_runtime.h>
#include <hip/hip_fp16.h>

#define EPS 1e-5f
#define CPAD 16  // cnt padded to one int per 64B line

typedef unsigned short ushort_t;

// ============== CSR build: hist(+rank) -> 3-phase scan -> bucket =============

__global__ void k_hist_rank(const int* __restrict__ col, int* __restrict__ cnt,
                            ushort_t* __restrict__ rank, int e) {
    int i = blockIdx.x * blockDim.x + threadIdx.x;
    if (i < e) {
        int old = atomicAdd(&cnt[(size_t)col[i] * CPAD], 1);
        rank[i] = (ushort_t)old;
    }
}

__global__ void k_scan_blocks(const int* __restrict__ cnt, int* __restrict__ bsum, int n) {
    __shared__ int ws[4];
    int t = threadIdx.x, lane = t & 63, wv = t >> 6;
    int i = blockIdx.x * 256 + t;
    int v = (i < n) ? cnt[(size_t)i * CPAD] : 0;
    int x = v;
#pragma unroll
    for (int off = 32; off; off >>= 1) x += __shfl_xor(x, off);
    if (lane == 0) ws[wv] = x;
    __syncthreads();
    if (t == 0) bsum[blockIdx.x] = ws[0] + ws[1] + ws[2] + ws[3];
}

__global__ void k_scan_top(const int* __restrict__ bsum, int* __restrict__ bofs,
                           int* __restrict__ start, int nb, int n) {
    __shared__ int s[1024];
    int t = threadIdx.x;
    int v = (t < nb) ? bsum[t] : 0;
    s[t] = v;
    __syncthreads();
    for (int off = 1; off < 1024; off <<= 1) {
        int y = (t >= off) ? s[t - off] : 0;
        __syncthreads();
        s[t] += y;
        __syncthreads();
    }
    if (t < nb) bofs[t] = s[t] - v;      // exclusive
    if (t == nb - 1) start[n] = s[t];    // grand total
}

__global__ void k_scan_apply(const int* __restrict__ cnt, const int* __restrict__ bofs,
                             int* __restrict__ start, float* __restrict__ dinv, int n) {
    __shared__ int ws[4];
    int t = threadIdx.x, lane = t & 63, wv = t >> 6;
    int i = blockIdx.x * 256 + t;
    int v = (i < n) ? cnt[(size_t)i * CPAD] : 0;
    int x = v;
#pragma unroll
    for (int off = 1; off < 64; off <<= 1) {
        int y = __shfl_up(x, off);
        if (lane >= off) x += y;
    }
    if (lane == 63) ws[wv] = x;
    __syncthreads();
    int wofs = 0;
#pragma unroll
    for (int w = 0; w < 4; ++w) wofs += (w < wv) ? ws[w] : 0;
    if (i < n) {
        start[i] = bofs[blockIdx.x] + wofs + (x - v);
        dinv[i] = rsqrtf((float)(v + 1));
    }
}

// bRow stored as uint16 (valid because N=50000 < 65536)
__global__ void k_bucket(const int* __restrict__ row, const int* __restrict__ col,
                         const int* __restrict__ start, const ushort_t* __restrict__ rank,
                         ushort_t* __restrict__ bRow, int e) {
    int i = blockIdx.x * blockDim.x + threadIdx.x;
    if (i < e) bRow[start[col[i]] + (int)rank[i]] = (ushort_t)row[i];
}

// ============== fused input MLP + layer-0 transform ==========================
// Paired layout: lane m (0..31) owns features (m, m+32); lanes 32-63 duplicate.
// h2[node*32+m] = float2{h_m, h_{m+32}}; ts[node*32+m] = half2{t_m, t_{m+32}}.

__global__ void k_mlp_transform(const float* __restrict__ x, const float* __restrict__ Win,
                                const float* __restrict__ bin, const float* __restrict__ Wc,
                                const float* __restrict__ dinv, float2* __restrict__ h2,
                                __half2* __restrict__ ts, int n) {
    int wv = threadIdx.x >> 6, lane = threadIdx.x & 63;
    int node = blockIdx.x * 4 + wv;
    if (node >= n) return;
    int sub = lane >> 5, m = lane & 31;
    float ax = bin[m], ay = bin[m + 32];
    const float* xr = x + (size_t)node * 16;
#pragma unroll
    for (int k = 0; k < 16; ++k) {
        float xv = xr[k];  // wave-uniform broadcast
        ax += xv * Win[k * 64 + m];
        ay += xv * Win[k * 64 + m + 32];
    }
    ax = fmaxf(ax, 0.0f);
    ay = fmaxf(ay, 0.0f);
    size_t idx = (size_t)node * 32 + m;
    if (!sub) h2[idx] = make_float2(ax, ay);
    // transform: each half computes its 32 k-terms, then combine across halves
    float tx = 0.f, ty = 0.f;
#pragma unroll
    for (int mp = 0; mp < 32; ++mp) {
        float ykx = __shfl(ax, mp);
        float yky = __shfl(ay, mp);
        float yk = sub ? yky : ykx;       // k = sub*32 + mp
        int k = (sub << 5) + mp;
        tx += yk * Wc[k * 64 + m];
        ty += yk * Wc[k * 64 + m + 32];
    }
    tx += __shfl_xor(tx, 32);
    ty += __shfl_xor(ty, 32);
    float dv = dinv[node];
    if (!sub) ts[idx] = __floats2half2_rn(tx * dv, ty * dv);
}

// ====== gather + LN + relu + residual + fused next-transform / output head ===
// 2 edges per wave-load: lanes 0-31 take edge j, lanes 32-63 take edge j+1.

__global__ void k_gather(const int* __restrict__ start, const ushort_t* __restrict__ bRow,
                         const __half2* __restrict__ ts, const float* __restrict__ dinv,
                         const float* __restrict__ bc, const float* __restrict__ gm,
                         const float* __restrict__ bt, float2* __restrict__ h2, int n,
                         const float* __restrict__ WcN, __half2* __restrict__ tsOut, int do_next,
                         const float* __restrict__ Wout, const float* __restrict__ bout,
                         float* __restrict__ out, int do_out) {
    int wv = threadIdx.x >> 6, lane = threadIdx.x & 63;
    int node = blockIdx.x * 4 + wv;
    if (node >= n) return;
    int sub = lane >> 5, m = lane & 31;
    int e0 = start[node], e1 = start[node + 1];
    float a0x = 0.f, a0y = 0.f, a1x = 0.f, a1y = 0.f;
    float a2x = 0.f, a2y = 0.f, a3x = 0.f, a3y = 0.f;
    for (int e = e0; e < e1; e += 64) {
        int cnt = min(64, e1 - e);
        int rE = (int)bRow[e + ((lane < cnt) ? lane : 0)];
        int j = 0;
        for (; j + 7 < cnt; j += 8) {  // 8 edges, 4 independent loads in flight
            int r0 = __shfl(rE, j + sub);
            int r1 = __shfl(rE, j + 2 + sub);
            int r2 = __shfl(rE, j + 4 + sub);
            int r3 = __shfl(rE, j + 6 + sub);
            __half2 v0 = ts[(size_t)r0 * 32 + m];
            __half2 v1 = ts[(size_t)r1 * 32 + m];
            __half2 v2 = ts[(size_t)r2 * 32 + m];
            __half2 v3 = ts[(size_t)r3 * 32 + m];
            a0x += __low2float(v0); a0y += __high2float(v0);
            a1x += __low2float(v1); a1y += __high2float(v1);
            a2x += __low2float(v2); a2y += __high2float(v2);
            a3x += __low2float(v3); a3y += __high2float(v3);
        }
        for (; j < cnt; j += 2) {  // tail, 2 edges (or 1) per step
            int jj = j + sub;
            int act = (jj < cnt) ? 1 : 0;
            int r = __shfl(rE, act ? jj : j);
            __half2 v = ts[(size_t)r * 32 + m];
            if (act) { a0x += __low2float(v); a0y += __high2float(v); }
        }
    }
    float accx = (a0x + a1x) + (a2x + a3x);
    float accy = (a0y + a1y) + (a2y + a3y);
    accx += __shfl_xor(accx, 32);
    accy += __shfl_xor(accy, 32);
    size_t idx = (size_t)node * 32 + m;
    __half2 self = ts[idx];
    float dv = dinv[node];
    float vx = (accx + __low2float(self)) * dv + bc[m];
    float vy = (accy + __high2float(self)) * dv + bc[m + 32];
    // layernorm over 64 features (2 per lane, reduce within 32-lane half)
    float s = vx + vy;
#pragma unroll
    for (int off = 16; off; off >>= 1) s += __shfl_xor(s, off);
    float mu = s * (1.0f / 64.0f);
    float dx = vx - mu, dy = vy - mu;
    float q = dx * dx + dy * dy;
#pragma unroll
    for (int off = 16; off; off >>= 1) q += __shfl_xor(q, off);
    float inv = rsqrtf(q * (1.0f / 64.0f) + EPS);
    float2 hv = h2[idx];
    float yx = fmaxf(dx * inv * gm[m] + bt[m], 0.0f) + hv.x;
    float yy = fmaxf(dy * inv * gm[m + 32] + bt[m + 32], 0.0f) + hv.y;
    if (!sub) h2[idx] = make_float2(yx, yy);
    if (do_next) {
        float tx = 0.f, ty = 0.f;
#pragma unroll
        for (int mp = 0; mp < 32; ++mp) {
            float ykx = __shfl(yx, mp);
            float yky = __shfl(yy, mp);
            float yk = sub ? yky : ykx;   // k = sub*32 + mp
            int k = (sub << 5) + mp;
            tx += yk * WcN[k * 64 + m];
            ty += yk * WcN[k * 64 + m + 32];
        }
        tx += __shfl_xor(tx, 32);
        ty += __shfl_xor(ty, 32);
        if (!sub) tsOut[idx] = __floats2half2_rn(tx * dv, ty * dv);
    }
    if (do_out) {
        float o = yx * Wout[m] + yy * Wout[m + 32];
#pragma unroll
        for (int off = 16; off; off >>= 1) o += __shfl_xor(o, off);
        if (lane == 0) out[node] = o + bout[0];
    }
}

extern "C" void kernel_launch(void* const* d_in, const int* in_sizes, int n_in,
                              void* d_out, int out_size, void* d_ws, size_t ws_size,
                              hipStream_t stream) {
    const float* x     = (const float*)d_in[0];
    const int*   eidx  = (const int*)d_in[1];
    const float* Win   = (const float*)d_in[2];
    const float* bin   = (const float*)d_in[3];
    const float* Wconv = (const float*)d_in[4];
    const float* bconv = (const float*)d_in[5];
    const float* gamma = (const float*)d_in[6];
    const float* beta  = (const float*)d_in[7];
    const float* Wout  = (const float*)d_in[8];
    const float* bout  = (const float*)d_in[9];
    float* out = (float*)d_out;

    const int N = in_sizes[0] / 16;
    const int E = in_sizes[1] / 2;
    const int L = in_sizes[4] / (64 * 64);

    const int* row = eidx;
    const int* col = eidx + E;

    char* ws = (char*)d_ws;
    size_t off = 0;
    auto alloc = [&](size_t bytes) -> void* {
        size_t p = off;
        off += (bytes + 255) & ~(size_t)255;
        return (void*)(ws + p);
    };
    int*      cnt    = (int*)alloc((size_t)N * CPAD * 4);
    ushort_t* rank   = (ushort_t*)alloc((size_t)E * 2);
    int*      bsum   = (int*)alloc(1024 * 4);
    int*      bofs   = (int*)alloc(1024 * 4);
    int*      startA = (int*)alloc((size_t)(N + 1) * 4);
    float*    dinv   = (float*)alloc((size_t)N * 4);
    ushort_t* bRow   = (ushort_t*)alloc((size_t)E * 2);
    float2*   h2     = (float2*)alloc((size_t)N * 32 * 8);
    __half2*  tsA    = (__half2*)alloc((size_t)N * 32 * 4);
    __half2*  tsB    = (__half2*)alloc((size_t)N * 32 * 4);
    (void)ws_size;

    const int BT = 256;
    int gE1  = (E + BT - 1) / BT;
    int gN64 = (N + 3) / 4;
    int nb   = (N + 255) / 256;  // scan blocks (<=1024)

    hipMemsetAsync(cnt, 0, (size_t)N * CPAD * 4, stream);
    k_hist_rank<<<gE1, BT, 0, stream>>>(col, cnt, rank, E);
    k_scan_blocks<<<nb, 256, 0, stream>>>(cnt, bsum, N);
    k_scan_top<<<1, 1024, 0, stream>>>(bsum, bofs, startA, nb, N);
    k_scan_apply<<<nb, 256, 0, stream>>>(cnt, bofs, startA, dinv, N);
    k_bucket<<<gE1, BT, 0, stream>>>(row, col, startA, rank, bRow, E);

    k_mlp_transform<<<gN64, BT, 0, stream>>>(x, Win, bin, Wconv, dinv, h2, tsA, N);

    __half2* bufs[2] = {tsA, tsB};
    for (int l = 0; l < L; ++l) {
        const float* bc = bconv + (size_t)l * 64;
        const float* gm = gamma + (size_t)l * 64;
        const float* bt = beta + (size_t)l * 64;
        int last = (l == L - 1);
        const float* WcN = last ? Wconv : Wconv + (size_t)(l + 1) * 64 * 64;
        k_gather<<<gN64, BT, 0, stream>>>(startA, bRow, bufs[l & 1], dinv, bc, gm, bt, h2, N,
                                          WcN, bufs[(l + 1) & 1], !last,
                                          Wout, bout, out, last);
    }
}